// Round 2
// baseline (836.376 us; speedup 1.0000x reference)
//
#include <hip/hip_runtime.h>
#include <stdint.h>

#define N_NODES 50000
#define N_EDGES 800000
#define NODE_TILES 782              // ceil(50000/64)

#define K1   266
#define SW1  296   // We1^T row stride (bf16 elems)
#define SE   72    // e-tile stride
#define SW2  72

// node kernels
#define SA1  200
#define SN1  200
#define SA2  264
#define SN2  264

typedef short bf16x8 __attribute__((ext_vector_type(8)));
typedef float f32x4  __attribute__((ext_vector_type(4)));

static __device__ __forceinline__ unsigned short f2bf(float f) {
  unsigned int x = __float_as_uint(f);
  unsigned int r = (x + 0x7fffu + ((x >> 16) & 1u)) >> 16;
  return (unsigned short)r;
}
static __device__ __forceinline__ float silu_f(float x) {
  return x / (1.0f + __expf(-x));
}
static __device__ __forceinline__ bf16x8 pack8(float4 u, float4 v) {
  bf16x8 w;
  w[0] = (short)f2bf(u.x); w[1] = (short)f2bf(u.y);
  w[2] = (short)f2bf(u.z); w[3] = (short)f2bf(u.w);
  w[4] = (short)f2bf(v.x); w[5] = (short)f2bf(v.y);
  w[6] = (short)f2bf(v.z); w[7] = (short)f2bf(v.w);
  return w;
}

// ---------------------------------------------------------------------------
// Kernel 1: edge phase, wave-autonomous 16-edge tiles.
// A-fragments gathered straight from global into registers; no in-loop
// __syncthreads. Weights staged once per block in LDS. 57 KB LDS -> 2 blk/CU.
// ---------------------------------------------------------------------------
__global__ __launch_bounds__(256, 2) void edge_kernel(
    const float* __restrict__ H, const float* __restrict__ xyz,
    const int* __restrict__ eidx, const float* __restrict__ estruct,
    const float* __restrict__ erest,
    const float* __restrict__ We1, const float* __restrict__ be1,
    const float* __restrict__ We2, const float* __restrict__ be2,
    const float* __restrict__ Wg1, const float* __restrict__ bg1,
    const float* __restrict__ Wg2, const float* __restrict__ bg2,
    float* __restrict__ agg)
{
  __shared__ unsigned short W1s[64 * SW1];   // We1^T [n][k]   37.9 KB
  __shared__ unsigned short W2s[64 * SW2];   // We2^T [n][k]    9.2 KB
  __shared__ unsigned short Es [4 * 16 * SE];// per-wave e tile 9.2 KB
  __shared__ float d2s[4][16];
  __shared__ float dls[4][16];
  __shared__ float gsm[4][16];

  const int tid  = threadIdx.x;
  const int lane = tid & 63;
  const int wv   = tid >> 6;
  const int lr   = lane & 15;
  const int lq   = lane >> 4;

  // ---- stage transposed weights (once per block) ----
  {
    int n = tid & 63, chunk = tid >> 6;
    for (int k = chunk * 74; k < chunk * 74 + 74; ++k)
      W1s[n * SW1 + k] = (k < K1) ? f2bf(We1[k * 64 + n]) : (unsigned short)0;
    for (int k = chunk * 18; k < chunk * 18 + 18; ++k)
      W2s[n * SW2 + k] = (k < 64) ? f2bf(We2[k * 64 + n]) : (unsigned short)0;
  }
  __syncthreads();

  // hoisted per-lane epilogue constants (n = f*16+lr)
  float bias1[4], w256r[4], w257r[4], bias2[4];
  #pragma unroll
  for (int f = 0; f < 4; ++f) {
    int n = f * 16 + lr;
    bias1[f] = be1[n];
    w256r[f] = We1[256 * 64 + n];
    w257r[f] = We1[257 * 64 + n];
    bias2[f] = be2[n];
  }
  unsigned short* Es_w = &Es[wv * 16 * SE];

  const int n_tiles = N_EDGES / 16;  // 50000
  for (int tile = blockIdx.x * 4 + wv; tile < n_tiles; tile += gridDim.x * 4) {
    const int e0 = tile * 16;
    const int e_lr = e0 + lr;
    const int ni = eidx[e_lr];
    const int nj = eidx[N_EDGES + e_lr];

    // ---- A-fragments straight from global (lane holds A[lr][lq*8..+7]) ----
    bf16x8 afrag[9];
    #pragma unroll
    for (int s = 0; s < 8; ++s) {
      int node = (s < 4) ? ni : nj;
      const float* p = H + (long)node * 128 + (s & 3) * 32 + lq * 8;
      float4 u = *(const float4*)p;
      float4 v = *(const float4*)(p + 4);
      afrag[s] = pack8(u, v);
    }
    {
      bf16x8 w = {0, 0, 0, 0, 0, 0, 0, 0};
      if (lq == 0) {           // k = 256..263 -> [d2(0), delta(0), struct0..5]
        #pragma unroll
        for (int c = 0; c < 6; ++c) w[2 + c] = (short)f2bf(estruct[e_lr * 8 + c]);
      } else if (lq == 1) {    // k = 264..271 -> [struct6, struct7, 0...]
        w[0] = (short)f2bf(estruct[e_lr * 8 + 6]);
        w[1] = (short)f2bf(estruct[e_lr * 8 + 7]);
      }
      afrag[8] = w;
    }

    // ---- geometry (lanes 0..15: lq==0 so ni/nj belong to edge lr) ----
    if (lane < 16) {
      float dx = xyz[ni * 3 + 0] - xyz[nj * 3 + 0];
      float dy = xyz[ni * 3 + 1] - xyz[nj * 3 + 1];
      float dz = xyz[ni * 3 + 2] - xyz[nj * 3 + 2];
      float d2 = dx * dx + dy * dy + dz * dz;
      float dist = sqrtf(d2 + 1e-9f);
      float rest = erest[e_lr];
      d2s[wv][lane] = d2;
      dls[wv][lane] = (dist - rest) / (rest + 1e-9f);
    }

    // ---- gate MLP fp32: 4 lanes per edge, 8 hidden units each ----
    {
      int el = lane >> 2, part = lane & 3;
      float g0 = d2s[wv][el];
      float g1 = dls[wv][el];
      float gs[8];
      #pragma unroll
      for (int c = 0; c < 8; ++c) gs[c] = estruct[(e0 + el) * 8 + c];
      float partial = 0.f;
      #pragma unroll
      for (int hh = 0; hh < 8; ++hh) {
        int h = part * 8 + hh;
        float a = bg1[h] + g0 * Wg1[0 * 32 + h] + g1 * Wg1[1 * 32 + h];
        #pragma unroll
        for (int c = 0; c < 8; ++c) a += gs[c] * Wg1[(2 + c) * 32 + h];
        partial += silu_f(a) * Wg2[h];
      }
      partial += __shfl_xor(partial, 1);
      partial += __shfl_xor(partial, 2);
      if (part == 0)
        gsm[wv][el] = 1.f / (1.f + __expf(-(partial + bg2[0])));
    }

    // ---- GEMM1: e = silu(e_in @ We1 + be1 + fp32 rank-1 corrections) ----
    f32x4 zero4 = {0.f, 0.f, 0.f, 0.f};
    f32x4 acc[4];
    #pragma unroll
    for (int f = 0; f < 4; ++f) acc[f] = zero4;
    #pragma unroll
    for (int s = 0; s < 9; ++s) {
      int kb = s * 32 + lq * 8;
      #pragma unroll
      for (int f = 0; f < 4; ++f) {
        bf16x8 b = *(const bf16x8*)&W1s[(f * 16 + lr) * SW1 + kb];
        acc[f] = __builtin_amdgcn_mfma_f32_16x16x32_bf16(afrag[s], b, acc[f], 0, 0, 0);
      }
    }
    #pragma unroll
    for (int f = 0; f < 4; ++f) {
      int n = f * 16 + lr;
      #pragma unroll
      for (int r = 0; r < 4; ++r) {
        int m = lq * 4 + r;
        float v = acc[f][r] + bias1[f] + d2s[wv][m] * w256r[f] + dls[wv][m] * w257r[f];
        Es_w[m * SE + n] = f2bf(silu_f(v));
      }
    }

    // ---- GEMM2: e_msg = silu(e @ We2 + be2) * g; scatter-add ----
    f32x4 acc2[4];
    #pragma unroll
    for (int f = 0; f < 4; ++f) acc2[f] = zero4;
    #pragma unroll
    for (int s = 0; s < 2; ++s) {
      int kb = s * 32 + lq * 8;
      bf16x8 a = *(const bf16x8*)&Es_w[lr * SE + kb];
      #pragma unroll
      for (int f = 0; f < 4; ++f) {
        bf16x8 b = *(const bf16x8*)&W2s[(f * 16 + lr) * SW2 + kb];
        acc2[f] = __builtin_amdgcn_mfma_f32_16x16x32_bf16(a, b, acc2[f], 0, 0, 0);
      }
    }
    int dst[4];
    #pragma unroll
    for (int r = 0; r < 4; ++r) dst[r] = eidx[e0 + lq * 4 + r];
    #pragma unroll
    for (int f = 0; f < 4; ++f) {
      int n = f * 16 + lr;
      #pragma unroll
      for (int r = 0; r < 4; ++r) {
        float v = silu_f(acc2[f][r] + bias2[f]) * gsm[wv][lq * 4 + r];
        atomicAdd(agg + (long)dst[r] * 64 + n, v);
      }
    }
  }
}

// ---------------------------------------------------------------------------
// Kernel 2: h1 = silu([H | agg] @ Wn1 + bn1), stored bf16 to workspace
// ---------------------------------------------------------------------------
__global__ __launch_bounds__(256, 1) void node1_kernel(
    const float* __restrict__ H, const float* __restrict__ agg,
    const float* __restrict__ Wn1, const float* __restrict__ bn1,
    unsigned short* __restrict__ h1)
{
  __shared__ unsigned short As[64 * SA1];
  __shared__ unsigned short Ws[256 * SN1];

  const int tid  = threadIdx.x;
  const int lane = tid & 63;
  const int wv   = tid >> 6;
  const int lr   = lane & 15;
  const int lq   = lane >> 4;
  const int m0   = wv * 16;
  const int n0   = blockIdx.x * 64;

  {
    int n = tid;
    for (int k = 0; k < 192; ++k)
      Ws[n * SN1 + k] = f2bf(Wn1[k * 256 + n]);
  }
  {
    int le = tid >> 2, part = tid & 3;
    int node = n0 + le; if (node >= N_NODES) node = N_NODES - 1;
    if (part < 2) {
      const float* src = H + (long)node * 128 + part * 64;
      unsigned short* dst = &As[le * SA1 + part * 64];
      #pragma unroll
      for (int q = 0; q < 64; q += 8) {
        float4 u = *(const float4*)(src + q);
        float4 v = *(const float4*)(src + q + 4);
        *(bf16x8*)(dst + q) = pack8(u, v);
      }
    } else if (part == 2) {
      const float* src = agg + (long)node * 64;
      unsigned short* dst = &As[le * SA1 + 128];
      #pragma unroll
      for (int q = 0; q < 64; q += 8) {
        float4 u = *(const float4*)(src + q);
        float4 v = *(const float4*)(src + q + 4);
        *(bf16x8*)(dst + q) = pack8(u, v);
      }
    }
  }
  __syncthreads();

  f32x4 zero4 = {0.f, 0.f, 0.f, 0.f};
  f32x4 acc[16];
  #pragma unroll
  for (int f = 0; f < 16; ++f) acc[f] = zero4;
  #pragma unroll
  for (int s = 0; s < 6; ++s) {
    int kb = s * 32 + lq * 8;
    bf16x8 a = *(const bf16x8*)&As[(m0 + lr) * SA1 + kb];
    #pragma unroll
    for (int f = 0; f < 16; ++f) {
      bf16x8 b = *(const bf16x8*)&Ws[(f * 16 + lr) * SN1 + kb];
      acc[f] = __builtin_amdgcn_mfma_f32_16x16x32_bf16(a, b, acc[f], 0, 0, 0);
    }
  }
  #pragma unroll
  for (int f = 0; f < 16; ++f) {
    int n = f * 16 + lr;
    float bias = bn1[n];
    #pragma unroll
    for (int r = 0; r < 4; ++r) {
      int m = m0 + lq * 4 + r;
      int node = n0 + m;
      if (node < N_NODES)
        h1[(long)node * 256 + n] = f2bf(silu_f(acc[f][r] + bias));
    }
  }
}

// ---------------------------------------------------------------------------
// Kernel 3: upd = h1 @ Wn2 + bn2; x = H + upd; out = LayerNorm(x)*g + b
// ---------------------------------------------------------------------------
__global__ __launch_bounds__(256, 1) void node2_kernel(
    const unsigned short* __restrict__ h1,
    const float* __restrict__ Wn2, const float* __restrict__ bn2,
    const float* __restrict__ H,
    const float* __restrict__ ln_g, const float* __restrict__ ln_b,
    float* __restrict__ out)
{
  __shared__ unsigned short As[64 * SA2];
  __shared__ unsigned short Ws[128 * SN2];

  const int tid  = threadIdx.x;
  const int lane = tid & 63;
  const int wv   = tid >> 6;
  const int lr   = lane & 15;
  const int lq   = lane >> 4;
  const int m0   = wv * 16;
  const int n0   = blockIdx.x * 64;

  {
    int n = tid & 127, half = tid >> 7;
    for (int k = half * 128; k < half * 128 + 128; ++k)
      Ws[n * SN2 + k] = f2bf(Wn2[k * 128 + n]);
  }
  {
    int le = tid >> 2, part = tid & 3;
    int node = n0 + le; if (node >= N_NODES) node = N_NODES - 1;
    const unsigned short* src = h1 + (long)node * 256 + part * 64;
    unsigned short* dst = &As[le * SA2 + part * 64];
    #pragma unroll
    for (int q = 0; q < 64; q += 8)
      *(bf16x8*)(dst + q) = *(const bf16x8*)(src + q);
  }
  __syncthreads();

  f32x4 zero4 = {0.f, 0.f, 0.f, 0.f};
  f32x4 acc[8];
  #pragma unroll
  for (int f = 0; f < 8; ++f) acc[f] = zero4;
  #pragma unroll
  for (int s = 0; s < 8; ++s) {
    int kb = s * 32 + lq * 8;
    bf16x8 a = *(const bf16x8*)&As[(m0 + lr) * SA2 + kb];
    #pragma unroll
    for (int f = 0; f < 8; ++f) {
      bf16x8 b = *(const bf16x8*)&Ws[(f * 16 + lr) * SN2 + kb];
      acc[f] = __builtin_amdgcn_mfma_f32_16x16x32_bf16(a, b, acc[f], 0, 0, 0);
    }
  }

  #pragma unroll
  for (int r = 0; r < 4; ++r) {
    int m = m0 + lq * 4 + r;
    int node = n0 + m;
    int nc = node < N_NODES ? node : N_NODES - 1;
    float x[8];
    float sum = 0.f, sumsq = 0.f;
    #pragma unroll
    for (int f = 0; f < 8; ++f) {
      int n = f * 16 + lr;
      float u = acc[f][r] + bn2[n];
      float xv = H[(long)nc * 128 + n] + u;
      x[f] = xv;
      sum += xv;
      sumsq += xv * xv;
    }
    #pragma unroll
    for (int o = 1; o < 16; o <<= 1) {
      sum   += __shfl_xor(sum, o);
      sumsq += __shfl_xor(sumsq, o);
    }
    float mu  = sum * (1.f / 128.f);
    float var = sumsq * (1.f / 128.f) - mu * mu;
    float rstd = rsqrtf(var + 1e-5f);
    if (node < N_NODES) {
      #pragma unroll
      for (int f = 0; f < 8; ++f) {
        int n = f * 16 + lr;
        out[(long)node * 128 + n] = (x[f] - mu) * rstd * ln_g[n] + ln_b[n];
      }
    }
  }
}

extern "C" void kernel_launch(void* const* d_in, const int* in_sizes, int n_in,
                              void* d_out, int out_size, void* d_ws, size_t ws_size,
                              hipStream_t stream) {
  const float* H       = (const float*)d_in[0];
  const float* xyz     = (const float*)d_in[1];
  const int*   eidx    = (const int*)d_in[2];
  const float* estruct = (const float*)d_in[3];
  const float* erest   = (const float*)d_in[4];
  const float* We1     = (const float*)d_in[5];
  const float* be1     = (const float*)d_in[6];
  const float* We2     = (const float*)d_in[7];
  const float* be2     = (const float*)d_in[8];
  const float* Wg1     = (const float*)d_in[9];
  const float* bg1     = (const float*)d_in[10];
  const float* Wg2     = (const float*)d_in[11];
  const float* bg2     = (const float*)d_in[12];
  const float* Wn1     = (const float*)d_in[13];
  const float* bn1     = (const float*)d_in[14];
  const float* Wn2     = (const float*)d_in[15];
  const float* bn2     = (const float*)d_in[16];
  const float* ln_g    = (const float*)d_in[17];
  const float* ln_b    = (const float*)d_in[18];

  float* agg = (float*)d_ws;                                        // 12.8 MB
  unsigned short* h1 = (unsigned short*)((char*)d_ws + (size_t)N_NODES * 64 * 4);
                                                                    // 25.6 MB
  float* out = (float*)d_out;

  hipMemsetAsync(agg, 0, (size_t)N_NODES * 64 * sizeof(float), stream);

  hipLaunchKernelGGL(edge_kernel, dim3(512), dim3(256), 0, stream,
                     H, xyz, eidx, estruct, erest, We1, be1, We2, be2,
                     Wg1, bg1, Wg2, bg2, agg);
  hipLaunchKernelGGL(node1_kernel, dim3(NODE_TILES), dim3(256), 0, stream,
                     H, agg, Wn1, bn1, h1);
  hipLaunchKernelGGL(node2_kernel, dim3(NODE_TILES), dim3(256), 0, stream,
                     h1, Wn2, bn2, H, ln_g, ln_b, out);
}